// Round 1
// baseline (167.244 us; speedup 1.0000x reference)
//
#include <hip/hip_runtime.h>

// Haar wavelet transform, single fused pass.
// x: (8, 64, 512, 512) f32 -> low, high: (8, 64, 256, 256) f32 each.
// low  = 0.5*(a+b+c+d)
// high = lh+hl+hh = 0.5*(3d - a - b - c)
// where a=x[2i,2j], b=x[2i,2j+1], c=x[2i+1,2j], d=x[2i+1,2j+1].

__global__ __launch_bounds__(256) void haar_kernel(
    const float* __restrict__ x,
    float* __restrict__ low,
    float* __restrict__ high,
    unsigned n_items)  // planes * 256 rows * 128 col-pairs
{
    unsigned idx = blockIdx.x * blockDim.x + threadIdx.x;
    const unsigned stride = gridDim.x * blockDim.x;
    for (; idx < n_items; idx += stride) {
        const unsigned jp = idx & 127u;          // col pair (covers out cols 2jp, 2jp+1)
        const unsigned i  = (idx >> 7) & 255u;   // out row
        const unsigned p  = idx >> 15;           // plane (b*64 + c)

        const unsigned in_base = p * 262144u + (2u * i) * 512u + 4u * jp;
        const float4 v0 = *reinterpret_cast<const float4*>(x + in_base);         // a0 b0 a1 b1
        const float4 v1 = *reinterpret_cast<const float4*>(x + in_base + 512u);  // c0 d0 c1 d1

        const float a0 = v0.x, b0 = v0.y, a1 = v0.z, b1 = v0.w;
        const float c0 = v1.x, d0 = v1.y, c1 = v1.z, d1 = v1.w;

        const float lo0 = 0.5f * (a0 + b0 + c0 + d0);
        const float lo1 = 0.5f * (a1 + b1 + c1 + d1);
        const float hi0 = 0.5f * (3.0f * d0 - a0 - b0 - c0);
        const float hi1 = 0.5f * (3.0f * d1 - a1 - b1 - c1);

        const unsigned obase = p * 65536u + i * 256u + 2u * jp;
        *reinterpret_cast<float2*>(low + obase)  = make_float2(lo0, lo1);
        *reinterpret_cast<float2*>(high + obase) = make_float2(hi0, hi1);
    }
}

extern "C" void kernel_launch(void* const* d_in, const int* in_sizes, int n_in,
                              void* d_out, int out_size, void* d_ws, size_t ws_size,
                              hipStream_t stream) {
    const float* x = (const float*)d_in[0];
    float* out = (float*)d_out;

    // out_size = 2 * 8*64*256*256 = 67,108,864 ; low first, then high.
    const unsigned half = (unsigned)(out_size / 2);   // 33,554,432
    float* low  = out;
    float* high = out + half;

    const unsigned n_items = half / 2;                // one item = 2 output pixels
    const int block = 256;
    const int grid = 2048;                            // 8 blocks/CU, grid-stride

    haar_kernel<<<grid, block, 0, stream>>>(x, low, high, n_items);
}

// Round 3
// 143.601 us; speedup vs baseline: 1.1646x; 1.1646x over previous
//
#include <hip/hip_runtime.h>

// Haar wavelet transform, single fused pass.
// x: (8, 64, 512, 512) f32 -> low, high: (8, 64, 256, 256) f32 each.
// low  = 0.5*(a+b+c+d)
// high = lh+hl+hh = 0.5*(3d - a - b - c)
// where a=x[2i,2j], b=x[2i,2j+1], c=x[2i+1,2j], d=x[2i+1,2j+1].
//
// One item = 4 output pixels: thread reads 2x 32B (two 16B vectors per input
// row), writes one 16B vector to low and one to high. All streams are
// touch-once -> non-temporal hints. Native clang vector type (ext_vector)
// because __builtin_nontemporal_* rejects HIP_vector_type structs.

typedef float f32x4 __attribute__((ext_vector_type(4)));

__global__ __launch_bounds__(256) void haar_kernel(
    const float* __restrict__ x,
    float* __restrict__ low,
    float* __restrict__ high,
    unsigned n_items)  // planes * 256 rows * 64 col-quads
{
    unsigned idx = blockIdx.x * blockDim.x + threadIdx.x;
    const unsigned stride = gridDim.x * blockDim.x;
    for (; idx < n_items; idx += stride) {
        const unsigned jq = idx & 63u;           // col quad (out cols 4jq..4jq+3)
        const unsigned i  = (idx >> 6) & 255u;   // out row
        const unsigned p  = idx >> 14;           // plane (b*64 + c)

        const unsigned in_base = p * 262144u + (2u * i) * 512u + 8u * jq;
        const f32x4* r0 = reinterpret_cast<const f32x4*>(x + in_base);         // row 2i
        const f32x4* r1 = reinterpret_cast<const f32x4*>(x + in_base + 512u);  // row 2i+1
        const f32x4 v00 = __builtin_nontemporal_load(r0);      // a0 b0 a1 b1
        const f32x4 v01 = __builtin_nontemporal_load(r0 + 1);  // a2 b2 a3 b3
        const f32x4 v10 = __builtin_nontemporal_load(r1);      // c0 d0 c1 d1
        const f32x4 v11 = __builtin_nontemporal_load(r1 + 1);  // c2 d2 c3 d3

        f32x4 lo, hi;
        lo.x = 0.5f * (v00.x + v00.y + v10.x + v10.y);
        hi.x = 0.5f * (3.0f * v10.y - v00.x - v00.y - v10.x);
        lo.y = 0.5f * (v00.z + v00.w + v10.z + v10.w);
        hi.y = 0.5f * (3.0f * v10.w - v00.z - v00.w - v10.z);
        lo.z = 0.5f * (v01.x + v01.y + v11.x + v11.y);
        hi.z = 0.5f * (3.0f * v11.y - v01.x - v01.y - v11.x);
        lo.w = 0.5f * (v01.z + v01.w + v11.z + v11.w);
        hi.w = 0.5f * (3.0f * v11.w - v01.z - v01.w - v11.z);

        const unsigned obase = p * 65536u + i * 256u + 4u * jq;
        __builtin_nontemporal_store(lo, reinterpret_cast<f32x4*>(low + obase));
        __builtin_nontemporal_store(hi, reinterpret_cast<f32x4*>(high + obase));
    }
}

extern "C" void kernel_launch(void* const* d_in, const int* in_sizes, int n_in,
                              void* d_out, int out_size, void* d_ws, size_t ws_size,
                              hipStream_t stream) {
    const float* x = (const float*)d_in[0];
    float* out = (float*)d_out;

    // out_size = 2 * 8*64*256*256 = 67,108,864 ; low first, then high.
    const unsigned half = (unsigned)(out_size / 2);   // 33,554,432
    float* low  = out;
    float* high = out + half;

    const unsigned n_items = half / 4;                // one item = 4 output pixels
    const int block = 256;
    const int grid = 2048;                            // 8 blocks/CU, grid-stride

    haar_kernel<<<grid, block, 0, stream>>>(x, low, high, n_items);
}